// Round 5
// baseline (606.166 us; speedup 1.0000x reference)
//
#include <hip/hip_runtime.h>
#include <stdint.h>

// Problem constants (fixed by setup_inputs in the reference)
#define BB 32
#define PP 24564
#define CC 81
#define OO 32

#define V0c 0.1f
#define V1c 0.2f

#define RW 16                    // rows per wave-chunk (16*324B = 5184B, 16B-aligned)
#define CH_F4 ((RW * CC) / 4)    // 324 float4 per chunk
#define NCHUNK (BB * PP / RW)    // 49128 chunks exactly (786048 rows)
#define CE_BLOCKS 3072           // 12288 waves, grid-stride: <=4 chunks per wave

// ---------------- workspace layout ----------------
// bt_idx  : int   [B*P]
// bt_ov   : float [B*P]
// lc      : float [B*P]
// bp_key  : u64   [B*O]
// ls_slots: float [64]
// cs_slots: float [64]
// num_pos : int   [32]

__global__ void k_init(unsigned long long* bp_key, float* ls_slots, float* cs_slots,
                       int* num_pos) {
    int i = blockIdx.x * 256 + threadIdx.x;
    if (i < BB * OO) bp_key[i] = 0ULL;
    if (i < 64) { ls_slots[i] = 0.0f; cs_slots[i] = 0.0f; }
    if (i < BB) num_pos[i] = 0;
}

// One thread per (b, prior): best-truth per prior only. No atomics.
__global__ __launch_bounds__(256) void k_match(const float4* __restrict__ priors,
                                               const float4* __restrict__ boxes,
                                               float* __restrict__ bt_ov,
                                               int* __restrict__ bt_idx) {
    int b = blockIdx.y;
    int p = blockIdx.x * 256 + threadIdx.x;

    __shared__ float4 s_box[OO];
    __shared__ float s_area[OO];

    if (threadIdx.x < OO) {
        float4 t = boxes[b * OO + threadIdx.x];
        s_box[threadIdx.x] = t;
        s_area[threadIdx.x] = (t.z - t.x) * (t.w - t.y);
    }
    __syncthreads();

    if (p < PP) {
        float4 pr = priors[p];  // center form
        float ax0 = pr.x - pr.z * 0.5f;
        float ay0 = pr.y - pr.w * 0.5f;
        float ax1 = pr.x + pr.z * 0.5f;
        float ay1 = pr.y + pr.w * 0.5f;
        float area_a = (ax1 - ax0) * (ay1 - ay0);

        float best = -1.0f;
        int bidx = 0;
        #pragma unroll 8
        for (int o = 0; o < OO; ++o) {
            float4 t = s_box[o];
            float lx = fmaxf(ax0, t.x), ly = fmaxf(ay0, t.y);
            float rx = fminf(ax1, t.z), ry = fminf(ay1, t.w);
            float w = fmaxf(rx - lx, 0.0f), h = fmaxf(ry - ly, 0.0f);
            float inter = w * h;
            float iou = inter / (area_a + s_area[o] - inter);
            if (iou > best) { best = iou; bidx = o; }  // first-max wins
        }
        bt_ov[b * PP + p] = best;
        bt_idx[b * PP + p] = bidx;
    }
}

// Grid (O, B, 8): each block scans 1/8 of priors for one (b,o); global atomicMax
// on packed (iou, ~p) key merges segments.
__global__ __launch_bounds__(256) void k_bestprior(const float4* __restrict__ priors,
                                                   const float4* __restrict__ boxes,
                                                   unsigned long long* __restrict__ bp_key) {
    int o = blockIdx.x;
    int b = blockIdx.y;
    const int NSEG = 8;
    const int SEG = (PP + NSEG - 1) / NSEG;
    int p0 = blockIdx.z * SEG;
    int p1 = p0 + SEG;
    if (p1 > PP) p1 = PP;

    float4 t = boxes[b * OO + o];
    float area_b = (t.z - t.x) * (t.w - t.y);

    unsigned long long best = 0ULL;
    for (int p = p0 + threadIdx.x; p < p1; p += 256) {
        float4 pr = priors[p];
        float ax0 = pr.x - pr.z * 0.5f;
        float ay0 = pr.y - pr.w * 0.5f;
        float ax1 = pr.x + pr.z * 0.5f;
        float ay1 = pr.y + pr.w * 0.5f;
        float area_a = (ax1 - ax0) * (ay1 - ay0);
        float lx = fmaxf(ax0, t.x), ly = fmaxf(ay0, t.y);
        float rx = fminf(ax1, t.z), ry = fminf(ay1, t.w);
        float w = fmaxf(rx - lx, 0.0f), h = fmaxf(ry - ly, 0.0f);
        float inter = w * h;
        float iou = inter / (area_a + area_b - inter);
        unsigned long long key = ((unsigned long long)__float_as_uint(iou) << 32) |
                                 (unsigned long long)(0xFFFFFFFFu - (unsigned int)p);
        best = (key > best) ? key : best;
    }
    #pragma unroll
    for (int off = 32; off; off >>= 1) {
        unsigned long long other = __shfl_down(best, off, 64);
        best = (other > best) ? other : best;
    }
    __shared__ unsigned long long s_w[4];
    int wid = threadIdx.x >> 6;
    if ((threadIdx.x & 63) == 0) s_w[wid] = best;
    __syncthreads();
    if (threadIdx.x == 0) {
        unsigned long long m = s_w[0];
        for (int i = 1; i < 4; ++i) m = (s_w[i] > m) ? s_w[i] : m;
        atomicMax(&bp_key[b * OO + o], m);
    }
}

// Serial per batch: force each truth's best prior; later truths win on duplicates.
__global__ void k_scatter(const unsigned long long* __restrict__ bp_key,
                          float* __restrict__ bt_ov, int* __restrict__ bt_idx) {
    int b = blockIdx.x * blockDim.x + threadIdx.x;
    if (b < BB) {
        for (int o = 0; o < OO; ++o) {
            unsigned long long key = bp_key[b * OO + o];
            unsigned int p = 0xFFFFFFFFu - (unsigned int)(key & 0xFFFFFFFFull);
            bt_idx[b * PP + p] = o;
            bt_ov[b * PP + p] = 2.0f;
        }
    }
}

// Wave-private 16-row chunks, grid-strided with bounds guard (wave-uniform).
// Global dwordx4 -> LDS -> wave_barrier (DS pipe is in-order per wave) ->
// 16-lane softmax. No block-wide barrier in the hot loop.
__global__ __launch_bounds__(256, 6) void k_ce(const float4* __restrict__ conf4,
                                               const float4* __restrict__ loc4,
                                               const float4* __restrict__ priors,
                                               const float4* __restrict__ boxes,
                                               const int* __restrict__ labels,
                                               const float* __restrict__ bt_ov,
                                               const int* __restrict__ bt_idx,
                                               float* __restrict__ lc,
                                               int* __restrict__ num_pos,
                                               float* __restrict__ ls_slots,
                                               float* __restrict__ cs_slots) {
    __shared__ __align__(16) float s_conf[4][RW * CC];  // 4 waves x 5184B
    __shared__ int s_idx[4][RW];
    __shared__ float s_ov[4][RW];
    __shared__ int s_lab[BB * OO];                      // 4KB label table

    for (int i = threadIdx.x; i < BB * OO; i += 256) s_lab[i] = labels[i];
    __syncthreads();  // once per kernel (label table only)

    int wave = threadIdx.x >> 6;
    int lane = threadIdx.x & 63;
    int g = lane >> 4;   // 16-lane group within wave
    int gl = lane & 15;  // lane within group
    float* sc = s_conf[wave];
    int wgid = blockIdx.x * 4 + wave;
    const int NWAVE = CE_BLOCKS * 4;

    for (int chunk = wgid; chunk < NCHUNK; chunk += NWAVE) {
        int r0 = chunk * RW;
        const float4* src = conf4 + (size_t)chunk * CH_F4;

        #pragma unroll
        for (int i = 0; i < 6; ++i) {
            int idx = lane + 64 * i;
            if (idx < CH_F4) ((float4*)sc)[idx] = src[idx];
        }
        if (lane < RW) {
            s_idx[wave][lane] = bt_idx[r0 + lane];
            s_ov[wave][lane] = bt_ov[r0 + lane];
        }
        __builtin_amdgcn_wave_barrier();  // order ds_write before ds_read (same wave)

        #pragma unroll
        for (int e = 0; e < 4; ++e) {
            int rl = 4 * g + e;
            const float* row = sc + rl * CC;
            float x[6];
            #pragma unroll
            for (int s = 0; s < 6; ++s) {
                int idx = gl + 16 * s;
                x[s] = (idx < CC) ? row[idx] : -INFINITY;
            }

            float m = fmaxf(fmaxf(fmaxf(x[0], x[1]), fmaxf(x[2], x[3])), fmaxf(x[4], x[5]));
            #pragma unroll
            for (int off = 1; off < 16; off <<= 1) m = fmaxf(m, __shfl_xor(m, off, 16));

            float sum = 0.0f;
            #pragma unroll
            for (int s = 0; s < 6; ++s) sum += __expf(x[s] - m);
            #pragma unroll
            for (int off = 1; off < 16; off <<= 1) sum += __shfl_xor(sum, off, 16);
            float lse = __logf(sum) + m;

            int r = r0 + rl;
            unsigned b = (unsigned)r / PP;  // magic-div
            int p = r - (int)b * PP;
            int t = s_idx[wave][rl];
            float ov = s_ov[wave][rl];
            int cls = s_lab[b * OO + t];
            if (ov < 0.5f) cls = 0;

            int slot = cls >> 4;
            float xs = x[0];
            #pragma unroll
            for (int s = 1; s < 6; ++s) xs = (slot == s) ? x[s] : xs;
            float xt = __shfl(xs, cls & 15, 16);
            float ce = lse - xt;

            if (gl == 0) {
                if (cls > 0) {
                    lc[r] = 0.0f;
                    atomicAdd(&num_pos[b], 1);
                    atomicAdd(&cs_slots[r & 63], ce);
                    float4 tb = boxes[b * OO + t];  // corner form
                    float4 pr = priors[p];          // center form
                    float gx = ((tb.x + tb.z) * 0.5f - pr.x) / (V0c * pr.z);
                    float gy = ((tb.y + tb.w) * 0.5f - pr.y) / (V0c * pr.w);
                    float gw = logf((tb.z - tb.x) / pr.z) / V1c;
                    float gh = logf((tb.w - tb.y) / pr.w) / V1c;
                    float4 lp = loc4[r];
                    float d0 = fabsf(lp.x - gx);
                    float d1 = fabsf(lp.y - gy);
                    float d2 = fabsf(lp.z - gw);
                    float d3 = fabsf(lp.w - gh);
                    float s = 0.0f;
                    s += (d0 < 1.0f) ? 0.5f * d0 * d0 : d0 - 0.5f;
                    s += (d1 < 1.0f) ? 0.5f * d1 * d1 : d1 - 0.5f;
                    s += (d2 < 1.0f) ? 0.5f * d2 * d2 : d2 - 0.5f;
                    s += (d3 < 1.0f) ? 0.5f * d3 * d3 : d3 - 0.5f;
                    atomicAdd(&ls_slots[r & 63], s);
                } else {
                    lc[r] = ce;
                }
            }
        }
        __builtin_amdgcn_wave_barrier();  // keep next chunk's writes after this compute
    }
}

// One block per batch: exact top-k sum of lc via 31-bit MSB radix select.
__global__ __launch_bounds__(1024) void k_select(const float* __restrict__ lc,
                                                 const int* __restrict__ num_pos,
                                                 float* __restrict__ cs_slots) {
    int b = blockIdx.x;
    const float* v = lc + (size_t)b * PP;
    int np = num_pos[b];
    long long k0 = 3LL * (long long)np;
    int k = (k0 < (long long)(PP - 1)) ? (int)k0 : (PP - 1);

    __shared__ int s_cnt[16];
    __shared__ float s_sum[16];
    __shared__ unsigned int s_prefix;
    __shared__ int s_k;

    unsigned int val[24];
    #pragma unroll
    for (int i = 0; i < 24; ++i) {
        int idx = threadIdx.x + i * 1024;
        val[i] = (idx < PP) ? __float_as_uint(v[idx]) : 0u;
    }

    if (k <= 0) return;  // uniform per block

    if (threadIdx.x == 0) { s_prefix = 0u; s_k = k; }
    __syncthreads();

    unsigned int prefix = 0u;
    for (int bit = 30; bit >= 0; --bit) {
        unsigned int cand = prefix | (1u << bit);
        unsigned int hi = cand >> bit;
        int c = 0;
        #pragma unroll
        for (int i = 0; i < 24; ++i) c += ((val[i] >> bit) == hi);
        #pragma unroll
        for (int off = 32; off; off >>= 1) c += __shfl_down(c, off, 64);
        int wid = threadIdx.x >> 6;
        if ((threadIdx.x & 63) == 0) s_cnt[wid] = c;
        __syncthreads();
        if (threadIdx.x == 0) {
            int tot = 0;
            #pragma unroll
            for (int i = 0; i < 16; ++i) tot += s_cnt[i];
            if (tot >= s_k) s_prefix = cand; else s_k -= tot;
        }
        __syncthreads();
        prefix = s_prefix;
    }

    float fv = __uint_as_float(prefix);
    float ssum = 0.0f;
    int cgt = 0;
    #pragma unroll
    for (int i = 0; i < 24; ++i) {
        if (val[i] > prefix) { ssum += __uint_as_float(val[i]); cgt++; }
    }
    #pragma unroll
    for (int off = 32; off; off >>= 1) {
        ssum += __shfl_down(ssum, off, 64);
        cgt += __shfl_down(cgt, off, 64);
    }
    int wid = threadIdx.x >> 6;
    if ((threadIdx.x & 63) == 0) { s_cnt[wid] = cgt; s_sum[wid] = ssum; }
    __syncthreads();
    if (threadIdx.x == 0) {
        int ct = 0;
        float st = 0.0f;
        #pragma unroll
        for (int i = 0; i < 16; ++i) { ct += s_cnt[i]; st += s_sum[i]; }
        float topk = st + (float)(k - ct) * fv;
        atomicAdd(&cs_slots[b], topk);  // b < 32: spread, 1 atomic/block
    }
}

__global__ void k_final(const int* __restrict__ num_pos,
                        const float* __restrict__ ls_slots,
                        const float* __restrict__ cs_slots,
                        float* __restrict__ out) {
    if (threadIdx.x == 0 && blockIdx.x == 0) {
        int N = 0;
        for (int b = 0; b < BB; ++b) N += num_pos[b];
        float Sl = 0.0f, Sc = 0.0f;
        for (int i = 0; i < 64; ++i) { Sl += ls_slots[i]; Sc += cs_slots[i]; }
        float fN = (float)N;
        out[0] = Sl / fN + Sc / fN;
    }
}

extern "C" void kernel_launch(void* const* d_in, const int* in_sizes, int n_in,
                              void* d_out, int out_size, void* d_ws, size_t ws_size,
                              hipStream_t stream) {
    const float* loc_preds = (const float*)d_in[0];   // [B,P,4]
    const float* conf_preds = (const float*)d_in[1];  // [B,P,C]
    const float* priors = (const float*)d_in[2];      // [P,4] center form
    const float* boxes = (const float*)d_in[3];       // [B,O,4] corner form
    const int* labels = (const int*)d_in[4];          // [B,O]

    char* ws = (char*)d_ws;
    const size_t SZ_BP = (size_t)BB * PP;
    int* bt_idx = (int*)(ws);
    float* bt_ov = (float*)(ws + SZ_BP * 4);
    float* lc = (float*)(ws + SZ_BP * 8);
    unsigned long long* bp_key = (unsigned long long*)(ws + SZ_BP * 12);
    float* ls_slots = (float*)(ws + SZ_BP * 12 + (size_t)BB * OO * 8);
    float* cs_slots = ls_slots + 64;
    int* num_pos = (int*)(cs_slots + 64);

    k_init<<<4, 256, 0, stream>>>(bp_key, ls_slots, cs_slots, num_pos);

    dim3 g1((PP + 255) / 256, BB);
    k_match<<<g1, 256, 0, stream>>>((const float4*)priors, (const float4*)boxes,
                                    bt_ov, bt_idx);

    dim3 g2(OO, BB, 8);
    k_bestprior<<<g2, 256, 0, stream>>>((const float4*)priors, (const float4*)boxes,
                                        bp_key);

    k_scatter<<<1, 64, 0, stream>>>(bp_key, bt_ov, bt_idx);

    k_ce<<<CE_BLOCKS, 256, 0, stream>>>((const float4*)conf_preds,
                                        (const float4*)loc_preds,
                                        (const float4*)priors, (const float4*)boxes,
                                        labels, bt_ov, bt_idx, lc, num_pos,
                                        ls_slots, cs_slots);

    k_select<<<BB, 1024, 0, stream>>>(lc, num_pos, cs_slots);

    k_final<<<1, 64, 0, stream>>>(num_pos, ls_slots, cs_slots, (float*)d_out);
}